// Round 1
// baseline (833.433 us; speedup 1.0000x reference)
//
#include <hip/hip_runtime.h>

#define NS 16384            // samples
#define ED 128              // embed dim
#define KC 10000            // clusters
#define KP 10240            // padded clusters
#define EKTOT (ED*KC)       // 1280000

// d_out layout (floats, concatenated in return order)
#define O_OUT  0
#define O_LOSS (NS*ED)              // 2097152
#define O_MEAN (O_LOSS+1)           // 2097153
#define O_SIZE (O_MEAN+EKTOT)       // 3377153
#define O_SUM  (O_SIZE+KC)          // 3387153

// scratch stashed inside the outputs region (consumed before k_gather overwrites it)
#define S_CNORM 0                   // KP floats
#define S_MVAL  KP                  // 2*NS floats
#define S_MIDX  (S_MVAL + 2*NS)     // 2*NS ints

// ws: idx ints at [0,NS), n_sample float at index NS
#define W_NSAMP NS

constexpr float DECAY = 0.99f;
constexpr float OMD   = 0.01f;   // 1 - DECAY
constexpr float EPSV  = 1e-5f;

__global__ void k_init(float* __restrict__ out, float* __restrict__ ws) {
    int i = blockIdx.x * 256 + threadIdx.x;
    if (i < EKTOT) out[O_SUM + i] = 0.f;
    else if (i < EKTOT + KC) out[O_SIZE + (i - EKTOT)] = 0.f;
    if (i == 0) { out[O_LOSS] = 0.f; ws[W_NSAMP] = 0.f; }
}

__global__ void k_cnorm(const float* __restrict__ M, float* __restrict__ out) {
    int k = blockIdx.x * 256 + threadIdx.x;   // < KP
    float s = __builtin_inff();
    if (k < KC) {
        s = 0.f;
        for (int e = 0; e < ED; ++e) { float m = M[(size_t)e*KC + k]; s = fmaf(m, m, s); }
    }
    out[S_CNORM + k] = s;
}

// 256 blocks: rb = row-block (128 rows), half = K-column half [0,5000)/[5000,10000)
__launch_bounds__(256, 1)
__global__ void k_assign(const float* __restrict__ X, const float* __restrict__ M,
                         float* __restrict__ out) {
    __shared__ float4 xs4[ED*32];   // xs[e][n], 64KB
    __shared__ float4 ms4[ED*32];   // ms[e][k], 64KB
    float* xs = (float*)xs4;

    const int b = blockIdx.x;
    const int half = b & 1, rb = b >> 1;
    const int n0 = rb * 128;
    const int kstart = half * 5000;
    const int t = threadIdx.x;
    const int ty = t >> 4, tx = t & 15;

    // stage X tile transposed: xs[e][n]  (one-time; bank conflicts here are amortized)
    #pragma unroll
    for (int rep = 0; rep < 16; ++rep) {
        int f = rep*256 + t;                  // 0..4095
        int n = f >> 5, e4 = (f & 31) << 2;
        float4 v = *(const float4*)(X + (size_t)(n0 + n)*ED + e4);
        xs[(e4+0)*128 + n] = v.x;
        xs[(e4+1)*128 + n] = v.y;
        xs[(e4+2)*128 + n] = v.z;
        xs[(e4+3)*128 + n] = v.w;
    }

    float best[8]; int bidx[8];
    #pragma unroll
    for (int i = 0; i < 8; ++i) { best[i] = __builtin_inff(); bidx[i] = 0; }

    for (int c = 0; c < 40; ++c) {
        int kbase = kstart + c*128;
        __syncthreads();
        if (kbase + 128 <= KC) {
            #pragma unroll
            for (int rep = 0; rep < 16; ++rep) {
                int f = rep*256 + t;
                int e = f >> 5, k4 = (f & 31) << 2;
                ms4[f] = *(const float4*)(M + (size_t)e*KC + kbase + k4);
            }
        } else {
            #pragma unroll
            for (int rep = 0; rep < 16; ++rep) {
                int f = rep*256 + t;
                int e = f >> 5, k4 = (f & 31) << 2;
                float4 v;
                v.x = (kbase+k4+0 < KC) ? M[(size_t)e*KC + kbase+k4+0] : 0.f;
                v.y = (kbase+k4+1 < KC) ? M[(size_t)e*KC + kbase+k4+1] : 0.f;
                v.z = (kbase+k4+2 < KC) ? M[(size_t)e*KC + kbase+k4+2] : 0.f;
                v.w = (kbase+k4+3 < KC) ? M[(size_t)e*KC + kbase+k4+3] : 0.f;
                ms4[f] = v;
            }
        }
        __syncthreads();

        float acc[8][8];
        #pragma unroll
        for (int i = 0; i < 8; ++i)
            #pragma unroll
            for (int j = 0; j < 8; ++j) acc[i][j] = 0.f;

        #pragma unroll 4
        for (int e = 0; e < ED; ++e) {
            float4 xa0 = xs4[e*32 + ty*2];
            float4 xa1 = xs4[e*32 + ty*2 + 1];
            float4 mb0 = ms4[e*32 + tx*2];
            float4 mb1 = ms4[e*32 + tx*2 + 1];
            float xr[8] = {xa0.x,xa0.y,xa0.z,xa0.w,xa1.x,xa1.y,xa1.z,xa1.w};
            float mr[8] = {mb0.x,mb0.y,mb0.z,mb0.w,mb1.x,mb1.y,mb1.z,mb1.w};
            #pragma unroll
            for (int i = 0; i < 8; ++i)
                #pragma unroll
                for (int j = 0; j < 8; ++j)
                    acc[i][j] = fmaf(xr[i], mr[j], acc[i][j]);
        }

        #pragma unroll
        for (int j = 0; j < 8; ++j) {
            int k = kbase + tx*8 + j;
            float cn = out[S_CNORM + k];          // +inf for k >= KC
            #pragma unroll
            for (int i = 0; i < 8; ++i) {
                float d = fmaf(-2.f, acc[i][j], cn);
                if (d < best[i]) { best[i] = d; bidx[i] = k; }  // ascending k: first-min kept
            }
        }
    }

    // reduce (val,idx) across the 16 tx lanes; lexicographic tie-break (lowest k)
    #pragma unroll
    for (int i = 0; i < 8; ++i) {
        float v = best[i]; int ix = bidx[i];
        #pragma unroll
        for (int off = 1; off < 16; off <<= 1) {
            float v2 = __shfl_xor(v, off);
            int   x2 = __shfl_xor(ix, off);
            if (v2 < v || (v2 == v && x2 < ix)) { v = v2; ix = x2; }
        }
        if (tx == 0) {
            int r = n0 + ty*8 + i;
            out[S_MVAL + half*NS + r] = v;
            ((int*)(out + S_MIDX))[half*NS + r] = ix;
        }
    }
}

__global__ void k_merge(const float* __restrict__ out, int* __restrict__ idx) {
    int n = blockIdx.x * 256 + threadIdx.x;
    if (n >= NS) return;
    float v0 = out[S_MVAL + n], v1 = out[S_MVAL + NS + n];
    const int* mi = (const int*)(out + S_MIDX);
    int i0 = mi[n], i1 = mi[NS + n];
    idx[n] = (v1 < v0 || (v1 == v0 && i1 < i0)) ? i1 : i0;
}

__global__ void k_scatter(const float* __restrict__ X, const int* __restrict__ idx,
                          float* __restrict__ out) {
    int tt = blockIdx.x * 256 + threadIdx.x;
    int n = tt >> 7, e = tt & 127;
    int k = idx[n];
    atomicAdd(out + O_SUM + (size_t)e*KC + k, X[tt] * OMD);
    if (e == 0) atomicAdd(out + O_SIZE + k, 1.0f);
}

__global__ void k_size(const float* __restrict__ csize, float* __restrict__ out,
                       float* __restrict__ ws) {
    __shared__ float red[256];
    int k = blockIdx.x * 256 + threadIdx.x;
    float nsz = 0.f;
    if (k < KC) {
        float c = out[O_SIZE + k];
        nsz = fmaf(csize[k], DECAY, c * OMD);
        out[O_SIZE + k] = nsz;
    }
    red[threadIdx.x] = nsz;
    __syncthreads();
    for (int s = 128; s > 0; s >>= 1) {
        if (threadIdx.x < s) red[threadIdx.x] += red[threadIdx.x + s];
        __syncthreads();
    }
    if (threadIdx.x == 0) atomicAdd(ws + W_NSAMP, red[0]);
}

__global__ void k_mean(const float* __restrict__ csum, float* __restrict__ out,
                       const float* __restrict__ ws) {
    int i = blockIdx.x * 256 + threadIdx.x;
    if (i >= EKTOT) return;
    int e = i / KC, k = i - e*KC;
    float seg = out[O_SUM + i];
    float ncs = fmaf(csum[i], DECAY, seg);
    out[O_SUM + i] = ncs;
    float nsz = out[O_SIZE + k];
    float ns = ws[W_NSAMP];
    float sm = (nsz + EPSV) * ns / (ns + (float)KC * EPSV);
    out[O_MEAN + i] = ncs / sm;
}

__global__ void k_gather(const float* __restrict__ X, const int* __restrict__ idx,
                         float* __restrict__ out) {
    __shared__ float red[256];
    int tt = blockIdx.x * 256 + threadIdx.x;
    int n = tt >> 7, e = tt & 127;
    int k = idx[n];
    float q = out[O_MEAN + (size_t)e*KC + k];
    float x = X[tt];
    out[O_OUT + tt] = x + (q - x);
    float d = x - q;
    red[threadIdx.x] = d * d;
    __syncthreads();
    for (int s = 128; s > 0; s >>= 1) {
        if (threadIdx.x < s) red[threadIdx.x] += red[threadIdx.x + s];
        __syncthreads();
    }
    if (threadIdx.x == 0)
        atomicAdd(out + O_LOSS, red[0] * (0.25f / (float)(NS * ED)));
}

extern "C" void kernel_launch(void* const* d_in, const int* in_sizes, int n_in,
                              void* d_out, int out_size, void* d_ws, size_t ws_size,
                              hipStream_t stream) {
    const float* X  = (const float*)d_in[0];   // inputs [16384,128]
    const float* M  = (const float*)d_in[1];   // cluster_mean [128,10000]
    const float* CS = (const float*)d_in[2];   // cluster_sum  [128,10000]
    const float* CZ = (const float*)d_in[3];   // cluster_size [10000]
    float* out = (float*)d_out;
    float* ws  = (float*)d_ws;
    int*   idx = (int*)d_ws;

    hipLaunchKernelGGL(k_init,    dim3((EKTOT+KC+255)/256), dim3(256), 0, stream, out, ws);
    hipLaunchKernelGGL(k_cnorm,   dim3(KP/256),             dim3(256), 0, stream, M, out);
    hipLaunchKernelGGL(k_assign,  dim3(256),                dim3(256), 0, stream, X, M, out);
    hipLaunchKernelGGL(k_merge,   dim3(NS/256),             dim3(256), 0, stream, out, idx);
    hipLaunchKernelGGL(k_scatter, dim3(NS*ED/256),          dim3(256), 0, stream, X, idx, out);
    hipLaunchKernelGGL(k_size,    dim3(KP/256),             dim3(256), 0, stream, CZ, out, ws);
    hipLaunchKernelGGL(k_mean,    dim3((EKTOT+255)/256),    dim3(256), 0, stream, CS, out, ws);
    hipLaunchKernelGGL(k_gather,  dim3(NS*ED/256),          dim3(256), 0, stream, X, idx, out);
}

// Round 2
// 676.578 us; speedup vs baseline: 1.2318x; 1.2318x over previous
//
#include <hip/hip_runtime.h>

#define NS 16384            // samples
#define ED 128              // embed dim
#define KC 10000            // clusters
#define KP 10240            // padded clusters (80 * 128)
#define EKTOT (ED*KC)       // 1280000

// d_out layout (floats, concatenated in return order)
#define O_OUT  0
#define O_LOSS (NS*ED)              // 2097152
#define O_MEAN (O_LOSS+1)           // 2097153
#define O_SIZE (O_MEAN+EKTOT)       // 3377153
#define O_SUM  (O_SIZE+KC)          // 3387153

// ws byte offsets (total needed ~13.9 MB)
#define WB_BEST  0u          // NS * u64 best (key<<32 | idx)
#define WB_CNORM 131072u     // KP * f32  (|m|^2, +inf for padding)
#define WB_IDX   172032u     // NS * i32
#define WB_NS    237568u     // 1 * f32 n_sample
#define WB_XH    262144u     // NS*ED f16
#define WB_XL    4456448u    // NS*ED f16
#define WB_MH    8650752u    // KP*ED f16 (transposed: [cluster][e])
#define WB_ML    11272192u   // KP*ED f16

typedef _Float16 f16;
typedef _Float16 f16x8 __attribute__((ext_vector_type(8)));
typedef _Float16 f16x4 __attribute__((ext_vector_type(4)));
typedef float f32x4 __attribute__((ext_vector_type(4)));

constexpr float DECAY = 0.99f;
constexpr float OMD   = 0.01f;   // 1 - DECAY
constexpr float EPSV  = 1e-5f;

__global__ void k_init(float* __restrict__ out, unsigned long long* __restrict__ best,
                       float* __restrict__ nsamp) {
    int i = blockIdx.x * 256 + threadIdx.x;
    if (i < EKTOT) out[O_SUM + i] = 0.f;
    else if (i < EKTOT + KC) out[O_SIZE + (i - EKTOT)] = 0.f;
    if (i < NS) best[i] = ~0ull;
    if (i == 0) { out[O_LOSS] = 0.f; *nsamp = 0.f; }
}

// split X into fp16 hi/lo, same [n][e] layout
__global__ void k_splitX(const float* __restrict__ X, f16* __restrict__ Xh,
                         f16* __restrict__ Xl) {
    int i = (blockIdx.x * 256 + threadIdx.x) * 4;
    float4 v = *(const float4*)(X + i);
    f16x4 h, l;
    h[0] = (f16)v.x; l[0] = (f16)(v.x - (float)h[0]);
    h[1] = (f16)v.y; l[1] = (f16)(v.y - (float)h[1]);
    h[2] = (f16)v.z; l[2] = (f16)(v.z - (float)h[2]);
    h[3] = (f16)v.w; l[3] = (f16)(v.w - (float)h[3]);
    *(f16x4*)(Xh + i) = h;
    *(f16x4*)(Xl + i) = l;
}

// split M into fp16 hi/lo, TRANSPOSED to [cluster][e]; also |m|^2 (fp32, same
// accumulation order as reference's axis-0 sum). Padding rows zeroed, cnorm=+inf.
__global__ void k_splitM(const float* __restrict__ M, f16* __restrict__ Mh,
                         f16* __restrict__ Ml, float* __restrict__ cnorm) {
    int k = blockIdx.x * 256 + threadIdx.x;   // < KP
    float s = __builtin_inff();
    f16 hb[ED], lb[ED];
    if (k < KC) {
        s = 0.f;
        #pragma unroll
        for (int e = 0; e < ED; ++e) {
            float m = M[e * KC + k];          // coalesced across lanes
            s = fmaf(m, m, s);
            f16 h = (f16)m;
            hb[e] = h;
            lb[e] = (f16)(m - (float)h);
        }
    } else {
        #pragma unroll
        for (int e = 0; e < ED; ++e) { hb[e] = (f16)0.f; lb[e] = (f16)0.f; }
    }
    cnorm[k] = s;
    #pragma unroll
    for (int e = 0; e < ED; e += 8) {
        *(f16x8*)(Mh + (size_t)k * ED + e) = *(const f16x8*)(hb + e);
        *(f16x8*)(Ml + (size_t)k * ED + e) = *(const f16x8*)(lb + e);
    }
}

// MFMA assign: D[n][c] = X[n]·M[c] via 3-pair fp16 split, argmin epilogue.
// m97 structure: 128x128 tile, BK=64, 4 waves (2x2) of 64x64, global_load_lds.
__launch_bounds__(256)
__global__ void k_assign(const f16* __restrict__ Xh, const f16* __restrict__ Xl,
                         const f16* __restrict__ Mh, const f16* __restrict__ Ml,
                         const float* __restrict__ cnorm,
                         unsigned long long* __restrict__ best) {
    __shared__ f16 As[128 * 64];   // 16KB: As[row][kk] kk<64
    __shared__ f16 Bs[128 * 64];   // 16KB: Bs[cluster_local][kk]

    const int c0 = blockIdx.x * 128;   // 80 col-blocks
    const int n0 = blockIdx.y * 128;   // 128 row-blocks
    const int t = threadIdx.x, w = t >> 6, l = t & 63;
    const int wr = w >> 1, wc = w & 1;
    const int lg = l >> 4, li = l & 15;

    f32x4 acc[4][4];
    #pragma unroll
    for (int i = 0; i < 4; ++i)
        #pragma unroll
        for (int j = 0; j < 4; ++j) acc[i][j] = (f32x4)0.f;

    const f16* Ap[3] = {Xh, Xh, Xl};
    const f16* Bp[3] = {Mh, Ml, Mh};

    for (int st = 0; st < 6; ++st) {           // 3 pairs x 2 K-halves of 64
        const int p = st >> 1, hh = st & 1;
        const f16* A = Ap[p];
        const f16* B = Bp[p];
        __syncthreads();                        // protect previous reads
        #pragma unroll
        for (int it = 0; it < 4; ++it) {
            int f = it * 256 + t;               // 16B-unit index 0..1023
            int row = f >> 3, seg = f & 7;
            const f16* ga = A + (size_t)(n0 + row) * ED + hh * 64 + seg * 8;
            const f16* gb = B + (size_t)(c0 + row) * ED + hh * 64 + seg * 8;
            f16* la = As + (it * 256 + w * 64) * 8;   // wave-uniform base
            f16* lb = Bs + (it * 256 + w * 64) * 8;
            __builtin_amdgcn_global_load_lds(
                (const __attribute__((address_space(1))) unsigned int*)ga,
                (__attribute__((address_space(3))) unsigned int*)la, 16, 0, 0);
            __builtin_amdgcn_global_load_lds(
                (const __attribute__((address_space(1))) unsigned int*)gb,
                (__attribute__((address_space(3))) unsigned int*)lb, 16, 0, 0);
        }
        __syncthreads();
        #pragma unroll
        for (int ks = 0; ks < 2; ++ks) {
            f16x8 a[4], b[4];
            #pragma unroll
            for (int i = 0; i < 4; ++i)
                a[i] = *(const f16x8*)(As + (wr * 64 + i * 16 + li) * 64 + ks * 32 + lg * 8);
            #pragma unroll
            for (int j = 0; j < 4; ++j)
                b[j] = *(const f16x8*)(Bs + (wc * 64 + j * 16 + li) * 64 + ks * 32 + lg * 8);
            #pragma unroll
            for (int i = 0; i < 4; ++i)
                #pragma unroll
                for (int j = 0; j < 4; ++j)
                    acc[i][j] = __builtin_amdgcn_mfma_f32_16x16x32_f16(a[i], b[j], acc[i][j], 0, 0, 0);
        }
    }

    // argmin epilogue: d = |m|^2 - 2 x·m  (|x|^2 constant per row, dropped).
    // C/D layout: col = li, row = lg*4 + reg (verified m89/m91).
    #pragma unroll
    for (int i = 0; i < 4; ++i) {
        #pragma unroll
        for (int r = 0; r < 4; ++r) {
            float bv = __builtin_inff(); int bc = 0;
            #pragma unroll
            for (int j = 0; j < 4; ++j) {
                int c = c0 + wc * 64 + j * 16 + li;
                float d = fmaf(-2.f, acc[i][j][r], cnorm[c]);
                if (d < bv) { bv = d; bc = c; }   // ascending c: first-min kept
            }
            #pragma unroll
            for (int off = 1; off < 16; off <<= 1) {
                float v2 = __shfl_xor(bv, off);
                int   c2 = __shfl_xor(bc, off);
                if (v2 < bv || (v2 == bv && c2 < bc)) { bv = v2; bc = c2; }
            }
            if (li == 0) {
                unsigned u = __float_as_uint(bv);
                u = (u & 0x80000000u) ? ~u : (u | 0x80000000u);  // order-preserving
                unsigned long long key = ((unsigned long long)u << 32) | (unsigned)bc;
                atomicMin(best + (n0 + wr * 64 + i * 16 + lg * 4 + r), key);
            }
        }
    }
}

__global__ void k_merge(const unsigned long long* __restrict__ best,
                        int* __restrict__ idx) {
    int n = blockIdx.x * 256 + threadIdx.x;
    if (n < NS) idx[n] = (int)(unsigned)(best[n] & 0xFFFFFFFFull);
}

__global__ void k_scatter(const float* __restrict__ X, const int* __restrict__ idx,
                          float* __restrict__ out) {
    int tt = blockIdx.x * 256 + threadIdx.x;
    int n = tt >> 7, e = tt & 127;
    int k = idx[n];
    atomicAdd(out + O_SUM + (size_t)e * KC + k, X[tt] * OMD);
    if (e == 0) atomicAdd(out + O_SIZE + k, 1.0f);
}

__global__ void k_size(const float* __restrict__ csize, float* __restrict__ out,
                       float* __restrict__ nsamp) {
    __shared__ float red[256];
    int k = blockIdx.x * 256 + threadIdx.x;
    float nsz = 0.f;
    if (k < KC) {
        float c = out[O_SIZE + k];
        nsz = fmaf(csize[k], DECAY, c * OMD);
        out[O_SIZE + k] = nsz;
    }
    red[threadIdx.x] = nsz;
    __syncthreads();
    for (int s = 128; s > 0; s >>= 1) {
        if (threadIdx.x < s) red[threadIdx.x] += red[threadIdx.x + s];
        __syncthreads();
    }
    if (threadIdx.x == 0) atomicAdd(nsamp, red[0]);
}

__global__ void k_mean(const float* __restrict__ csum, float* __restrict__ out,
                       const float* __restrict__ nsamp) {
    int i = blockIdx.x * 256 + threadIdx.x;
    if (i >= EKTOT) return;
    int e = i / KC, k = i - e * KC;
    float seg = out[O_SUM + i];
    float ncs = fmaf(csum[i], DECAY, seg);
    out[O_SUM + i] = ncs;
    float nsz = out[O_SIZE + k];
    float ns = *nsamp;
    float sm = (nsz + EPSV) * ns / (ns + (float)KC * EPSV);
    out[O_MEAN + i] = ncs / sm;
}

__global__ void k_gather(const float* __restrict__ X, const int* __restrict__ idx,
                         float* __restrict__ out) {
    __shared__ float red[256];
    int tt = blockIdx.x * 256 + threadIdx.x;
    int n = tt >> 7, e = tt & 127;
    int k = idx[n];
    float q = out[O_MEAN + (size_t)e * KC + k];
    float x = X[tt];
    out[O_OUT + tt] = x + (q - x);
    float d = x - q;
    red[threadIdx.x] = d * d;
    __syncthreads();
    for (int s = 128; s > 0; s >>= 1) {
        if (threadIdx.x < s) red[threadIdx.x] += red[threadIdx.x + s];
        __syncthreads();
    }
    if (threadIdx.x == 0)
        atomicAdd(out + O_LOSS, red[0] * (0.25f / (float)(NS * ED)));
}

extern "C" void kernel_launch(void* const* d_in, const int* in_sizes, int n_in,
                              void* d_out, int out_size, void* d_ws, size_t ws_size,
                              hipStream_t stream) {
    const float* X  = (const float*)d_in[0];   // inputs [16384,128]
    const float* M  = (const float*)d_in[1];   // cluster_mean [128,10000]
    const float* CS = (const float*)d_in[2];   // cluster_sum  [128,10000]
    const float* CZ = (const float*)d_in[3];   // cluster_size [10000]
    float* out = (float*)d_out;

    char* wsb = (char*)d_ws;
    unsigned long long* best = (unsigned long long*)(wsb + WB_BEST);
    float* cnorm = (float*)(wsb + WB_CNORM);
    int*   idx   = (int*)(wsb + WB_IDX);
    float* nsamp = (float*)(wsb + WB_NS);
    f16* Xh = (f16*)(wsb + WB_XH);
    f16* Xl = (f16*)(wsb + WB_XL);
    f16* Mh = (f16*)(wsb + WB_MH);
    f16* Ml = (f16*)(wsb + WB_ML);

    hipLaunchKernelGGL(k_init,   dim3((EKTOT + KC + 255) / 256), dim3(256), 0, stream, out, best, nsamp);
    hipLaunchKernelGGL(k_splitX, dim3(NS * ED / 4 / 256),        dim3(256), 0, stream, X, Xh, Xl);
    hipLaunchKernelGGL(k_splitM, dim3(KP / 256),                 dim3(256), 0, stream, M, Mh, Ml, cnorm);
    hipLaunchKernelGGL(k_assign, dim3(KP / 128, NS / 128),       dim3(256), 0, stream, Xh, Xl, Mh, Ml, cnorm, best);
    hipLaunchKernelGGL(k_merge,  dim3(NS / 256),                 dim3(256), 0, stream, best, idx);
    hipLaunchKernelGGL(k_scatter,dim3(NS * ED / 256),            dim3(256), 0, stream, X, idx, out);
    hipLaunchKernelGGL(k_size,   dim3(KP / 256),                 dim3(256), 0, stream, CZ, out, nsamp);
    hipLaunchKernelGGL(k_mean,   dim3((EKTOT + 255) / 256),      dim3(256), 0, stream, CS, out, nsamp);
    hipLaunchKernelGGL(k_gather, dim3(NS * ED / 256),            dim3(256), 0, stream, X, idx, out);
}

// Round 3
// 473.805 us; speedup vs baseline: 1.7590x; 1.4280x over previous
//
#include <hip/hip_runtime.h>

#define NS 16384            // samples
#define ED 128              // embed dim
#define KC 10000            // clusters
#define KP 10240            // padded clusters (80 * 128)
#define EKTOT (ED*KC)       // 1280000

// d_out layout (floats, concatenated in return order)
#define O_OUT  0
#define O_LOSS (NS*ED)              // 2097152
#define O_MEAN (O_LOSS+1)           // 2097153
#define O_SIZE (O_MEAN+EKTOT)       // 3377153
#define O_SUM  (O_SIZE+KC)          // 3387153

// ws byte offsets (total needed ~13.9 MB)
#define WB_BEST  0u          // NS * u64 best (key<<32 | idx)
#define WB_CNORM 131072u     // KP * f32  (|m|^2, +inf for padding)
#define WB_IDX   172032u     // NS * i32
#define WB_NS    237568u     // 1 * f32 n_sample
#define WB_XH    262144u     // NS*ED f16
#define WB_XL    4456448u    // NS*ED f16
#define WB_MH    8650752u    // KP*ED f16 (transposed: [cluster][e])
#define WB_ML    11272192u   // KP*ED f16

typedef _Float16 f16;
typedef _Float16 f16x8 __attribute__((ext_vector_type(8)));
typedef _Float16 f16x4 __attribute__((ext_vector_type(4)));
typedef float f32x4 __attribute__((ext_vector_type(4)));

constexpr float DECAY = 0.99f;
constexpr float OMD   = 0.01f;   // 1 - DECAY
constexpr float EPSV  = 1e-5f;

__global__ void k_init(float* __restrict__ out, unsigned long long* __restrict__ best,
                       float* __restrict__ nsamp) {
    int i = blockIdx.x * 256 + threadIdx.x;
    if (i < EKTOT) out[O_SUM + i] = 0.f;
    else if (i < EKTOT + KC) out[O_SIZE + (i - EKTOT)] = 0.f;
    if (i < NS) best[i] = ~0ull;
    if (i == 0) { out[O_LOSS] = 0.f; *nsamp = 0.f; }
}

// split X into fp16 hi/lo, same [n][e] layout
__global__ void k_splitX(const float* __restrict__ X, f16* __restrict__ Xh,
                         f16* __restrict__ Xl) {
    int i = (blockIdx.x * 256 + threadIdx.x) * 4;
    float4 v = *(const float4*)(X + i);
    f16x4 h, l;
    h[0] = (f16)v.x; l[0] = (f16)(v.x - (float)h[0]);
    h[1] = (f16)v.y; l[1] = (f16)(v.y - (float)h[1]);
    h[2] = (f16)v.z; l[2] = (f16)(v.z - (float)h[2]);
    h[3] = (f16)v.w; l[3] = (f16)(v.w - (float)h[3]);
    *(f16x4*)(Xh + i) = h;
    *(f16x4*)(Xl + i) = l;
}

// split M into fp16 hi/lo, TRANSPOSED to [cluster][e]; also |m|^2 (fp32, same
// accumulation order as reference's axis-0 sum). Padding rows zeroed, cnorm=+inf.
__global__ void k_splitM(const float* __restrict__ M, f16* __restrict__ Mh,
                         f16* __restrict__ Ml, float* __restrict__ cnorm) {
    int k = blockIdx.x * 256 + threadIdx.x;   // < KP
    float s = __builtin_inff();
    f16 hb[ED], lb[ED];
    if (k < KC) {
        s = 0.f;
        #pragma unroll
        for (int e = 0; e < ED; ++e) {
            float m = M[e * KC + k];          // coalesced across lanes
            s = fmaf(m, m, s);
            f16 h = (f16)m;
            hb[e] = h;
            lb[e] = (f16)(m - (float)h);
        }
    } else {
        #pragma unroll
        for (int e = 0; e < ED; ++e) { hb[e] = (f16)0.f; lb[e] = (f16)0.f; }
    }
    cnorm[k] = s;
    #pragma unroll
    for (int e = 0; e < ED; e += 8) {
        *(f16x8*)(Mh + (size_t)k * ED + e) = *(const f16x8*)(hb + e);
        *(f16x8*)(Ml + (size_t)k * ED + e) = *(const f16x8*)(lb + e);
    }
}

// MFMA assign: D[n][c] = X[n]·M[c] via 3-pair fp16 split, argmin epilogue.
// m97 structure + T2 XOR swizzle (rule #21: linear LDS dest via global_load_lds,
// inverse-swizzled GLOBAL source, swizzled ds_read column).
__launch_bounds__(256, 4)
__global__ void k_assign(const f16* __restrict__ Xh, const f16* __restrict__ Xl,
                         const f16* __restrict__ Mh, const f16* __restrict__ Ml,
                         const float* __restrict__ cnorm,
                         unsigned long long* __restrict__ best) {
    __shared__ f16 As[128 * 64];   // 16KB: As[row][kk^swz]
    __shared__ f16 Bs[128 * 64];   // 16KB

    const int c0 = blockIdx.x * 128;   // 80 col-blocks
    const int n0 = blockIdx.y * 128;   // 128 row-blocks
    const int t = threadIdx.x, w = t >> 6, l = t & 63;
    const int wr = w >> 1, wc = w & 1;
    const int lg = l >> 4, li = l & 15;

    f32x4 acc[4][4];
    #pragma unroll
    for (int i = 0; i < 4; ++i)
        #pragma unroll
        for (int j = 0; j < 4; ++j) acc[i][j] = (f32x4)0.f;

    // stage order: (Xh,Mh),(Xh,Ml),(Xl,Mh) per K-half -> A unchanged at st=1,4
    const f16* Ap[6] = {Xh, Xh, Xl, Xh, Xh, Xl};
    const f16* Bp[6] = {Mh, Ml, Mh, Mh, Ml, Mh};

    for (int st = 0; st < 6; ++st) {
        const int hh = st < 3 ? 0 : 1;
        const bool loadA = (st != 1) && (st != 4);
        const f16* A = Ap[st];
        const f16* B = Bp[st];
        __syncthreads();                        // protect previous reads
        #pragma unroll
        for (int it = 0; it < 4; ++it) {
            int f = it * 256 + t;               // 16B-chunk index 0..1023
            int row = f >> 3, seg = f & 7;
            int segS = seg ^ (row & 7);         // inverse swizzle on SOURCE
            const f16* gb = B + (size_t)(c0 + row) * ED + hh * 64 + segS * 8;
            f16* lb = Bs + (it * 256 + w * 64) * 8;   // wave-uniform base, linear
            __builtin_amdgcn_global_load_lds(
                (const __attribute__((address_space(1))) unsigned int*)gb,
                (__attribute__((address_space(3))) unsigned int*)lb, 16, 0, 0);
            if (loadA) {
                const f16* ga = A + (size_t)(n0 + row) * ED + hh * 64 + segS * 8;
                f16* la = As + (it * 256 + w * 64) * 8;
                __builtin_amdgcn_global_load_lds(
                    (const __attribute__((address_space(1))) unsigned int*)ga,
                    (__attribute__((address_space(3))) unsigned int*)la, 16, 0, 0);
            }
        }
        __syncthreads();
        #pragma unroll
        for (int ks = 0; ks < 2; ++ks) {
            f16x8 a[4], b[4];
            #pragma unroll
            for (int i = 0; i < 4; ++i) {
                int r = wr * 64 + i * 16 + li;
                a[i] = *(const f16x8*)(As + r * 64 + ((ks * 32 + lg * 8) ^ ((r & 7) << 3)));
            }
            #pragma unroll
            for (int j = 0; j < 4; ++j) {
                int r = wc * 64 + j * 16 + li;
                b[j] = *(const f16x8*)(Bs + r * 64 + ((ks * 32 + lg * 8) ^ ((r & 7) << 3)));
            }
            #pragma unroll
            for (int i = 0; i < 4; ++i)
                #pragma unroll
                for (int j = 0; j < 4; ++j)
                    acc[i][j] = __builtin_amdgcn_mfma_f32_16x16x32_f16(a[i], b[j], acc[i][j], 0, 0, 0);
        }
    }

    // argmin epilogue: d = |m|^2 - 2 x·m  (|x|^2 constant per row, dropped).
    // C/D layout: col = li, row = lg*4 + reg (verified m89/m91).
    #pragma unroll
    for (int i = 0; i < 4; ++i) {
        #pragma unroll
        for (int r = 0; r < 4; ++r) {
            float bv = __builtin_inff(); int bc = 0;
            #pragma unroll
            for (int j = 0; j < 4; ++j) {
                int c = c0 + wc * 64 + j * 16 + li;
                float d = fmaf(-2.f, acc[i][j][r], cnorm[c]);
                if (d < bv) { bv = d; bc = c; }   // ascending c: first-min kept
            }
            #pragma unroll
            for (int off = 1; off < 16; off <<= 1) {
                float v2 = __shfl_xor(bv, off);
                int   c2 = __shfl_xor(bc, off);
                if (v2 < bv || (v2 == bv && c2 < bc)) { bv = v2; bc = c2; }
            }
            if (li == 0) {
                unsigned u = __float_as_uint(bv);
                u = (u & 0x80000000u) ? ~u : (u | 0x80000000u);  // order-preserving
                unsigned long long key = ((unsigned long long)u << 32) | (unsigned)bc;
                atomicMin(best + (n0 + wr * 64 + i * 16 + lg * 4 + r), key);
            }
        }
    }
}

__global__ void k_merge(const unsigned long long* __restrict__ best,
                        int* __restrict__ idx) {
    int n = blockIdx.x * 256 + threadIdx.x;
    if (n < NS) idx[n] = (int)(unsigned)(best[n] & 0xFFFFFFFFull);
}

__global__ void k_scatter(const float* __restrict__ X, const int* __restrict__ idx,
                          float* __restrict__ out) {
    int tt = blockIdx.x * 256 + threadIdx.x;
    int n = tt >> 7, e = tt & 127;
    int k = idx[n];
    atomicAdd(out + O_SUM + (size_t)e * KC + k, X[tt] * OMD);
    if (e == 0) atomicAdd(out + O_SIZE + k, 1.0f);
}

__global__ void k_size(const float* __restrict__ csize, float* __restrict__ out,
                       float* __restrict__ nsamp) {
    __shared__ float red[256];
    int k = blockIdx.x * 256 + threadIdx.x;
    float nsz = 0.f;
    if (k < KC) {
        float c = out[O_SIZE + k];
        nsz = fmaf(csize[k], DECAY, c * OMD);
        out[O_SIZE + k] = nsz;
    }
    red[threadIdx.x] = nsz;
    __syncthreads();
    for (int s = 128; s > 0; s >>= 1) {
        if (threadIdx.x < s) red[threadIdx.x] += red[threadIdx.x + s];
        __syncthreads();
    }
    if (threadIdx.x == 0) atomicAdd(nsamp, red[0]);
}

__global__ void k_mean(const float* __restrict__ csum, float* __restrict__ out,
                       const float* __restrict__ nsamp) {
    int i = blockIdx.x * 256 + threadIdx.x;
    if (i >= EKTOT) return;
    int e = i / KC, k = i - e * KC;
    float seg = out[O_SUM + i];
    float ncs = fmaf(csum[i], DECAY, seg);
    out[O_SUM + i] = ncs;
    float nsz = out[O_SIZE + k];
    float ns = *nsamp;
    float sm = (nsz + EPSV) * ns / (ns + (float)KC * EPSV);
    out[O_MEAN + i] = ncs / sm;
}

__global__ void k_gather(const float* __restrict__ X, const int* __restrict__ idx,
                         float* __restrict__ out) {
    __shared__ float red[256];
    int tt = blockIdx.x * 256 + threadIdx.x;
    int n = tt >> 7, e = tt & 127;
    int k = idx[n];
    float q = out[O_MEAN + (size_t)e * KC + k];
    float x = X[tt];
    out[O_OUT + tt] = x + (q - x);
    float d = x - q;
    red[threadIdx.x] = d * d;
    __syncthreads();
    for (int s = 128; s > 0; s >>= 1) {
        if (threadIdx.x < s) red[threadIdx.x] += red[threadIdx.x + s];
        __syncthreads();
    }
    if (threadIdx.x == 0)
        atomicAdd(out + O_LOSS, red[0] * (0.25f / (float)(NS * ED)));
}

extern "C" void kernel_launch(void* const* d_in, const int* in_sizes, int n_in,
                              void* d_out, int out_size, void* d_ws, size_t ws_size,
                              hipStream_t stream) {
    const float* X  = (const float*)d_in[0];   // inputs [16384,128]
    const float* M  = (const float*)d_in[1];   // cluster_mean [128,10000]
    const float* CS = (const float*)d_in[2];   // cluster_sum  [128,10000]
    const float* CZ = (const float*)d_in[3];   // cluster_size [10000]
    float* out = (float*)d_out;

    char* wsb = (char*)d_ws;
    unsigned long long* best = (unsigned long long*)(wsb + WB_BEST);
    float* cnorm = (float*)(wsb + WB_CNORM);
    int*   idx   = (int*)(wsb + WB_IDX);
    float* nsamp = (float*)(wsb + WB_NS);
    f16* Xh = (f16*)(wsb + WB_XH);
    f16* Xl = (f16*)(wsb + WB_XL);
    f16* Mh = (f16*)(wsb + WB_MH);
    f16* Ml = (f16*)(wsb + WB_ML);

    hipLaunchKernelGGL(k_init,   dim3((EKTOT + KC + 255) / 256), dim3(256), 0, stream, out, best, nsamp);
    hipLaunchKernelGGL(k_splitX, dim3(NS * ED / 4 / 256),        dim3(256), 0, stream, X, Xh, Xl);
    hipLaunchKernelGGL(k_splitM, dim3(KP / 256),                 dim3(256), 0, stream, M, Mh, Ml, cnorm);
    hipLaunchKernelGGL(k_assign, dim3(KP / 128, NS / 128),       dim3(256), 0, stream, Xh, Xl, Mh, Ml, cnorm, best);
    hipLaunchKernelGGL(k_merge,  dim3(NS / 256),                 dim3(256), 0, stream, best, idx);
    hipLaunchKernelGGL(k_scatter,dim3(NS * ED / 256),            dim3(256), 0, stream, X, idx, out);
    hipLaunchKernelGGL(k_size,   dim3(KP / 256),                 dim3(256), 0, stream, CZ, out, nsamp);
    hipLaunchKernelGGL(k_mean,   dim3((EKTOT + 255) / 256),      dim3(256), 0, stream, CS, out, nsamp);
    hipLaunchKernelGGL(k_gather, dim3(NS * ED / 256),            dim3(256), 0, stream, X, idx, out);
}